// Round 4
// baseline (442.026 us; speedup 1.0000x reference)
//
#include <hip/hip_runtime.h>
#include <math.h>

#define TT 40          // total query tokens (sum of q_seqlens)
#define NB 16          // batch
#define HQn 16         // query heads
#define HKn 8          // kv heads
#define Gn 2           // GQA group
#define Dn 256         // head dim
#define HID 3072
#define QKV_COLS 8192  // 4096 + 2048 + 2048
#define NCHUNK 16
#define CHUNKT 128

// ---------------- K1: QKV partial GEMM ----------------
// grid 512 = 32 col-tiles(256) * 16 k-splits(192), block 256
__global__ __launch_bounds__(256) void k1_qkv_gemm(
    const float* __restrict__ hs, const float* __restrict__ Wq,
    const float* __restrict__ Wk, const float* __restrict__ Wv,
    float* __restrict__ part1) {
  const int tile = blockIdx.x & 31;
  const int ks = blockIdx.x >> 5;
  const int c0 = tile << 8;
  const float* W; int ld, cw0;
  if (tile < 16)      { W = Wq; ld = 4096; cw0 = c0; }
  else if (tile < 24) { W = Wk; ld = 2048; cw0 = c0 - 4096; }
  else                { W = Wv; ld = 2048; cw0 = c0 - 6144; }
  const int kbase = ks * 192;
  const int cq = (threadIdx.x & 63) << 2;
  const int r0 = (threadIdx.x >> 6) * 10;
  __shared__ float h_lds[40][64];   // [token][k] : coalesced staging, broadcast reads
  float acc[10][4];
#pragma unroll
  for (int r = 0; r < 10; ++r) { acc[r][0]=0.f; acc[r][1]=0.f; acc[r][2]=0.f; acc[r][3]=0.f; }
  for (int kc = 0; kc < 192; kc += 64) {
    __syncthreads();
    for (int i = threadIdx.x; i < 2560; i += 256) {
      int t = i >> 6, kk = i & 63;
      h_lds[t][kk] = hs[t * HID + kbase + kc + kk];
    }
    __syncthreads();
    const float* wp = W + (size_t)(kbase + kc) * ld + cw0 + cq;
#pragma unroll 8
    for (int kk = 0; kk < 64; ++kk) {
      float4 w4 = *reinterpret_cast<const float4*>(wp + (size_t)kk * ld);
#pragma unroll
      for (int r = 0; r < 10; ++r) {
        float h = h_lds[r0 + r][kk];
        acc[r][0] = fmaf(h, w4.x, acc[r][0]);
        acc[r][1] = fmaf(h, w4.y, acc[r][1]);
        acc[r][2] = fmaf(h, w4.z, acc[r][2]);
        acc[r][3] = fmaf(h, w4.w, acc[r][3]);
      }
    }
  }
#pragma unroll
  for (int r = 0; r < 10; ++r) {
    int t = r0 + r;
    float4 v = make_float4(acc[r][0], acc[r][1], acc[r][2], acc[r][3]);
    *reinterpret_cast<float4*>(&part1[(size_t)(ks * TT + t) * QKV_COLS + c0 + cq]) = v;
  }
}

// ---------------- K2: k-split reduce + RoPE ----------------
// grid 1280 = 40 tokens * 32 tiles, block 256
__global__ __launch_bounds__(256) void k2_reduce_rope(
    const float* __restrict__ part1, const float* __restrict__ inv_freq,
    const int* __restrict__ pos_ids,
    float* __restrict__ qbuf, float* __restrict__ kbuf, float* __restrict__ vbuf) {
  const int t = blockIdx.x >> 5;
  const int tile = blockIdx.x & 31;
  const int c = (tile << 8) + threadIdx.x;
  float s = 0.f;
#pragma unroll
  for (int ks = 0; ks < 16; ++ks) s += part1[(size_t)(ks * TT + t) * QKV_COLS + c];
  __shared__ float sl[256];
  sl[threadIdx.x] = s;
  __syncthreads();
  if (tile < 24) {   // q or k head: apply neox RoPE
    const int d = threadIdx.x;
    const int d2 = d & 127;
    float fr = (float)pos_ids[t] * inv_freq[d2];
    float cs = cosf(fr), sn = sinf(fr);
    float v = (d < 128) ? (sl[d] * cs - sl[d + 128] * sn)
                        : (sl[d] * cs + sl[d - 128] * sn);
    if (tile < 16) qbuf[t * 4096 + (tile << 8) + d] = v * 0.0625f;  // fold 1/sqrt(D)
    else           kbuf[t * 2048 + ((tile - 16) << 8) + d] = v;
  } else {
    vbuf[t * 2048 + ((tile - 24) << 8) + threadIdx.x] = s;
  }
}

// ---------------- K3: flash-decode attention partials ----------------
// shuffle-free phase 1 (LDS dgrp-partials), ping-pong pipelined loads.
// grid 2048 = b(16)*hk(8)*chunk(16 of 128 toks), block 256 (4 waves)
__global__ __launch_bounds__(256, 4) void k3_attn_partial(
    const float* __restrict__ qbuf, const float* __restrict__ kbuf,
    const float* __restrict__ vbuf, const float* __restrict__ k_cache,
    const float* __restrict__ v_cache, const int* __restrict__ blk_off,
    const int* __restrict__ q_start, const int* __restrict__ q_lens,
    const int* __restrict__ kv_lens,
    float* __restrict__ part_o, float* __restrict__ part_ml) {
  const int chunk = blockIdx.x & 15;
  const int hk = (blockIdx.x >> 4) & 7;
  const int b = blockIdx.x >> 7;
  const int kv_len = kv_lens[b];
  const int cs0 = chunk * CHUNKT;
  if (cs0 >= kv_len) return;
  const int q_cnt = q_lens[b];
  const int hist = kv_len - q_cnt;
  const int q0 = q_start[b];
  const int nq = q_cnt * 2;

  __shared__ float buf[4][32][65];   // phase1: per-wave dgrp partials; phase3: o-combine
  __shared__ float S_lds[128][8];    // final scores -> p values (in place)
  __shared__ float red[32][8];
  __shared__ float Mg[8];

  const int tid = threadIdx.x;
  const int w = tid >> 6;
  const int lane = tid & 63;

  // chunk spans exactly 2 cache blocks: preload both -> pure-arith addressing
  const int bi = (b << 5) + (cs0 >> 6);
  const int blk0v = blk_off[bi];
  const int blk1v = blk_off[bi + 1];
  const float* kb0  = k_cache + ((size_t)blk0v << 17) + ((size_t)hk << 8);
  const float* kb1  = k_cache + ((size_t)blk1v << 17) + ((size_t)hk << 8);
  const float* vb0  = v_cache + ((size_t)blk0v << 17) + ((size_t)hk << 8);
  const float* vb1  = v_cache + ((size_t)blk1v << 17) + ((size_t)hk << 8);
  const float* knew = kbuf + ((size_t)q0 << 11) + ((size_t)hk << 8);
  const float* vnew = vbuf + ((size_t)q0 << 11) + ((size_t)hk << 8);

  auto rowK = [&](int s) -> const float* {
    if (s < hist) {
      const float* base = (s & 64) ? kb1 : kb0;
      return base + ((size_t)(s & 63) << 11);
    }
    return knew + ((size_t)(s - hist) << 11);
  };
  auto rowV = [&](int s) -> const float* {
    if (s < hist) {
      const float* base = (s & 64) ? vb1 : vb0;
      return base + ((size_t)(s & 63) << 11);
    }
    return vnew + ((size_t)(s - hist) << 11);
  };

  // init scores to -inf (rows never written must stay masked)
#pragma unroll
  for (int i = tid; i < 1024; i += 256) ((float*)S_lds)[i] = -1e30f;

  // ---- phase 1: scores. lane = qv(0..7) + 8*dgrp(0..7); wave handles 32 tokens.
  const int qv = lane & 7;
  const int dgrp = lane >> 3;
  const int qtok = min(qv >> 1, q_cnt - 1);
  const int g = qv & 1;
  float4 qf[8];
  {
    const float* qp = qbuf + (size_t)(q0 + qtok) * 4096 + (hk * Gn + g) * 256 + dgrp * 32;
#pragma unroll
    for (int j = 0; j < 8; ++j)
      qf[j] = *reinterpret_cast<const float4*>(qp + j * 4);
  }
  __syncthreads();

  const int sBeg = cs0 + w * 32;
  const int sEnd = min(cs0 + (w + 1) * 32, kv_len);
  const int nv = (sEnd > sBeg) ? (sEnd - sBeg) : 0;

  {
    float4 KA[8], KB[8];
    auto loadK = [&](int sv, float4* R) {
      const float* p_ = rowK(sv) + (dgrp << 5);
#pragma unroll
      for (int j = 0; j < 8; ++j) R[j] = *reinterpret_cast<const float4*>(p_ + (j << 2));
    };
    auto scoreK = [&](int sv, const float4* R) {
      float s0 = 0.f, s1 = 0.f;
#pragma unroll
      for (int j = 0; j < 4; ++j) {
        s0 = fmaf(qf[j].x, R[j].x, s0); s0 = fmaf(qf[j].y, R[j].y, s0);
        s0 = fmaf(qf[j].z, R[j].z, s0); s0 = fmaf(qf[j].w, R[j].w, s0);
      }
#pragma unroll
      for (int j = 4; j < 8; ++j) {
        s1 = fmaf(qf[j].x, R[j].x, s1); s1 = fmaf(qf[j].y, R[j].y, s1);
        s1 = fmaf(qf[j].z, R[j].z, s1); s1 = fmaf(qf[j].w, R[j].w, s1);
      }
      buf[w][sv - sBeg][lane] = s0 + s1;   // conflict-free b32 write
    };
    int s = sBeg;
    const int pairs = nv >> 1;
    if (pairs > 0) {
      loadK(s, KA); loadK(s + 1, KB);
      for (int p = 0; p < pairs - 1; ++p) {
        scoreK(s, KA); loadK(s + 2, KA);
        scoreK(s + 1, KB); loadK(s + 3, KB);
        s += 2;
      }
      scoreK(s, KA); scoreK(s + 1, KB); s += 2;
    }
    if (nv & 1) { loadK(s, KA); scoreK(s, KA); }
  }
  __syncthreads();

  // ---- phase 1b: wave-local reduce of 8 dgrp partials -> masked scores
  {
    const int tl = lane >> 3;
#pragma unroll
    for (int it = 0; it < 4; ++it) {
      int t = tl + (it << 3);
      if (t < nv) {
        int sabs = sBeg + t;
        float sum = 0.f;
#pragma unroll
        for (int dg = 0; dg < 8; ++dg) sum += buf[w][t][qv + (dg << 3)];
        bool valid = (qv < nq) && ((sabs - hist) <= (qv >> 1));
        S_lds[sabs - cs0][qv] = valid ? sum : -1e30f;
      }
    }
  }
  __syncthreads();

  // ---- phase 2: chunk-global softmax. thread tid: qv2 = tid&7, grp = tid>>3 (4 toks)
  const int qv2 = tid & 7;
  const int grp = tid >> 3;
  {
    float mloc = -1e30f;
#pragma unroll
    for (int t = 0; t < 4; ++t) mloc = fmaxf(mloc, S_lds[grp * 4 + t][qv2]);
    red[grp][qv2] = mloc;
  }
  __syncthreads();
  if (tid < 8) {
    float M = -1e30f;
#pragma unroll
    for (int i = 0; i < 32; ++i) M = fmaxf(M, red[i][tid]);
    Mg[tid] = M;
  }
  __syncthreads();
  {
    float M = Mg[qv2];
    float lloc = 0.f;
#pragma unroll
    for (int t = 0; t < 4; ++t) {
      int s = grp * 4 + t;
      float p = __expf(S_lds[s][qv2] - M);
      S_lds[s][qv2] = p;
      lloc += p;
    }
    red[grp][qv2] = lloc;
  }
  __syncthreads();
  if (tid < 8) {
    float L = 0.f;
#pragma unroll
    for (int i = 0; i < 32; ++i) L += red[i][tid];
    int pidx = (((b * HKn + hk) * NCHUNK + chunk) << 3) + tid;
    part_ml[pidx * 2] = Mg[tid];
    part_ml[pidx * 2 + 1] = L;
  }

  // ---- phase 3: PV. lane owns 4 dims; wave owns its 32 tokens; quad ping-pong.
  float4 acc[8];
#pragma unroll
  for (int q = 0; q < 8; ++q) acc[q] = make_float4(0.f, 0.f, 0.f, 0.f);
  const int d4 = lane << 2;
  {
    auto pv1 = [&](int sv, const float4 vf) {
      const int sl = sv - cs0;
      float4 p0 = *reinterpret_cast<const float4*>(&S_lds[sl][0]);
      float4 p1 = *reinterpret_cast<const float4*>(&S_lds[sl][4]);
      float p_[8] = {p0.x, p0.y, p0.z, p0.w, p1.x, p1.y, p1.z, p1.w};
#pragma unroll
      for (int q = 0; q < 8; ++q) {
        acc[q].x = fmaf(p_[q], vf.x, acc[q].x);
        acc[q].y = fmaf(p_[q], vf.y, acc[q].y);
        acc[q].z = fmaf(p_[q], vf.z, acc[q].z);
        acc[q].w = fmaf(p_[q], vf.w, acc[q].w);
      }
    };
    float4 VA[4], VB[4];
    auto loadV4 = [&](int s0v, float4* R) {
#pragma unroll
      for (int t = 0; t < 4; ++t)
        R[t] = *reinterpret_cast<const float4*>(rowV(s0v + t) + d4);
    };
    auto pv4 = [&](int s0v, const float4* R) {
      pv1(s0v, R[0]); pv1(s0v + 1, R[1]); pv1(s0v + 2, R[2]); pv1(s0v + 3, R[3]);
    };
    const int q4 = nv >> 2;
    if (q4 > 0) {
      loadV4(sBeg, VA);
      for (int p = 0; p < q4; ++p) {
        if (p & 1) {
          if (p + 1 < q4) loadV4(sBeg + ((p + 1) << 2), VA);
          pv4(sBeg + (p << 2), VB);
        } else {
          if (p + 1 < q4) loadV4(sBeg + ((p + 1) << 2), VB);
          pv4(sBeg + (p << 2), VA);
        }
      }
    }
    for (int s3 = sBeg + (q4 << 2); s3 < sEnd; ++s3) {
      float4 vf = *reinterpret_cast<const float4*>(rowV(s3) + d4);
      pv1(s3, vf);
    }
  }
  // o partials -> reuse buf as [4][8][256]
  float* o_l = &buf[0][0][0];
#pragma unroll
  for (int q = 0; q < 8; ++q)
    *reinterpret_cast<float4*>(&o_l[(w * 8 + q) * 256 + d4]) = acc[q];
  __syncthreads();

  // combine 4 wave-partials (same max within chunk -> plain sum)
  for (int q = 0; q < nq; ++q) {
    float o = o_l[q * 256 + tid] + o_l[(8 + q) * 256 + tid]
            + o_l[(16 + q) * 256 + tid] + o_l[(24 + q) * 256 + tid];
    int pidx = (((b * HKn + hk) * NCHUNK + chunk) << 3) + q;
    part_o[(size_t)pidx * 256 + tid] = o;
  }
}

// ---------------- K4: combine chunk partials ----------------
// grid 1024 = b(16)*qtok(4)*h(16), block 64
__global__ __launch_bounds__(64) void k4_attn_reduce(
    const float* __restrict__ part_o, const float* __restrict__ part_ml,
    const int* __restrict__ q_start, const int* __restrict__ q_lens,
    const int* __restrict__ kv_lens, float* __restrict__ attn_out) {
  const int h = blockIdx.x & 15;
  const int qtok = (blockIdx.x >> 4) & 3;
  const int b = blockIdx.x >> 6;
  const int q_cnt = q_lens[b];
  if (qtok >= q_cnt) return;
  const int kv_len = kv_lens[b];
  const int nparts = (kv_len + CHUNKT - 1) >> 7;
  const int qv = qtok * 2 + (h & 1);
  const int hk = h >> 1;
  const int lane = threadIdx.x;
  const int pbase = ((b * HKn + hk) * NCHUNK) << 3;
  float2 mls[16];
#pragma unroll
  for (int i = 0; i < 16; ++i)
    if (i < nparts)
      mls[i] = *reinterpret_cast<const float2*>(&part_ml[(size_t)(pbase + (i << 3) + qv) * 2]);
  float M = -1e30f;
#pragma unroll
  for (int i = 0; i < 16; ++i)
    if (i < nparts) M = fmaxf(M, mls[i].x);
  float4 o = make_float4(0.f, 0.f, 0.f, 0.f);
  float L = 0.f;
#pragma unroll
  for (int i = 0; i < 16; ++i)
    if (i < nparts) {
      float corr = __expf(mls[i].x - M);
      L += corr * mls[i].y;
      float4 pv = *reinterpret_cast<const float4*>(
          &part_o[(size_t)(pbase + (i << 3) + qv) * 256 + (lane << 2)]);
      o.x = fmaf(corr, pv.x, o.x);
      o.y = fmaf(corr, pv.y, o.y);
      o.z = fmaf(corr, pv.z, o.z);
      o.w = fmaf(corr, pv.w, o.w);
    }
  float inv = 1.0f / L;
  int tr = q_start[b] + qtok;
  float4 res = make_float4(o.x * inv, o.y * inv, o.z * inv, o.w * inv);
  *reinterpret_cast<float4*>(&attn_out[((size_t)tr * HQn + h) * 256 + (lane << 2)]) = res;
}

// ---------------- K5: output GEMM partial (attn @ Wo) ----------------
// grid 384 = 12 col-tiles(256) * 32 k-splits(128), block 256
__global__ __launch_bounds__(256) void k5_out_gemm(
    const float* __restrict__ ain, const float* __restrict__ Wo,
    float* __restrict__ part2) {
  const int tile = blockIdx.x % 12;
  const int ks = blockIdx.x / 12;
  const int c0 = tile << 8;
  const int kbase = ks << 7;
  const int cq = (threadIdx.x & 63) << 2;
  const int r0 = (threadIdx.x >> 6) * 10;
  __shared__ float h_lds[40][64];
  float acc[10][4];
#pragma unroll
  for (int r = 0; r < 10; ++r) { acc[r][0]=0.f; acc[r][1]=0.f; acc[r][2]=0.f; acc[r][3]=0.f; }
  for (int kc = 0; kc < 128; kc += 64) {
    __syncthreads();
    for (int i = threadIdx.x; i < 2560; i += 256) {
      int t = i >> 6, kk = i & 63;
      h_lds[t][kk] = ain[(size_t)t * 4096 + kbase + kc + kk];
    }
    __syncthreads();
    const float* wp = Wo + (size_t)(kbase + kc) * 3072 + c0 + cq;
#pragma unroll 8
    for (int kk = 0; kk < 64; ++kk) {
      float4 w4 = *reinterpret_cast<const float4*>(wp + (size_t)kk * 3072);
#pragma unroll
      for (int r = 0; r < 10; ++r) {
        float h = h_lds[r0 + r][kk];
        acc[r][0] = fmaf(h, w4.x, acc[r][0]);
        acc[r][1] = fmaf(h, w4.y, acc[r][1]);
        acc[r][2] = fmaf(h, w4.z, acc[r][2]);
        acc[r][3] = fmaf(h, w4.w, acc[r][3]);
      }
    }
  }
#pragma unroll
  for (int r = 0; r < 10; ++r) {
    int t = r0 + r;
    float4 v = make_float4(acc[r][0], acc[r][1], acc[r][2], acc[r][3]);
    *reinterpret_cast<float4*>(&part2[(size_t)(ks * TT + t) * 3072 + c0 + cq]) = v;
  }
}

// ---------------- K6: final k-split reduce -> d_out ----------------
// grid 480, block 256  (40*3072 = 122880 outputs)
__global__ __launch_bounds__(256) void k6_final_reduce(
    const float* __restrict__ part2, float* __restrict__ out) {
  const int idx = blockIdx.x * 256 + threadIdx.x;
  float s = 0.f;
#pragma unroll
  for (int ks = 0; ks < 32; ++ks) s += part2[(size_t)ks * 122880 + idx];
  out[idx] = s;
}

extern "C" void kernel_launch(void* const* d_in, const int* in_sizes, int n_in,
                              void* d_out, int out_size, void* d_ws, size_t ws_size,
                              hipStream_t stream) {
  const float* hs       = (const float*)d_in[0];
  const float* Wq       = (const float*)d_in[1];
  const float* Wk       = (const float*)d_in[2];
  const float* Wv       = (const float*)d_in[3];
  const float* Wo       = (const float*)d_in[4];
  const float* k_cache  = (const float*)d_in[5];
  const float* v_cache  = (const float*)d_in[6];
  const float* inv_freq = (const float*)d_in[7];
  const int*   pos_ids  = (const int*)d_in[8];
  const int*   q_start  = (const int*)d_in[9];
  const int*   q_lens   = (const int*)d_in[10];
  const int*   kv_lens  = (const int*)d_in[11];
  const int*   blk_off  = (const int*)d_in[12];

  float* ws = (float*)d_ws;
  float* qbuf     = ws;                 // 40*4096          = 163840
  float* kbuf     = ws + 163840;        // 40*2048          =  81920
  float* vbuf     = ws + 245760;        // 40*2048          =  81920
  float* attn_out = ws + 327680;        // 40*4096          = 163840
  float* big      = ws + 491520;        // reused region (5242880 floats)
  float* part1    = big;                // 16*40*8192
  float* part_o   = big;                // 16384*256
  float* part_ml  = big + 4194304;      // 16384*2
  float* part2    = big;                // 32*40*3072
  float* out      = (float*)d_out;

  k1_qkv_gemm<<<512, 256, 0, stream>>>(hs, Wq, Wk, Wv, part1);
  k2_reduce_rope<<<1280, 256, 0, stream>>>(part1, inv_freq, pos_ids, qbuf, kbuf, vbuf);
  k3_attn_partial<<<2048, 256, 0, stream>>>(qbuf, kbuf, vbuf, k_cache, v_cache,
                                            blk_off, q_start, q_lens, kv_lens,
                                            part_o, part_ml);
  k4_attn_reduce<<<1024, 64, 0, stream>>>(part_o, part_ml, q_start, q_lens,
                                          kv_lens, attn_out);
  k5_out_gemm<<<384, 256, 0, stream>>>(attn_out, Wo, part2);
  k6_final_reduce<<<480, 256, 0, stream>>>(part2, out);
}

// Round 5
// 297.820 us; speedup vs baseline: 1.4842x; 1.4842x over previous
//
#include <hip/hip_runtime.h>
#include <math.h>

#define TT 40          // total query tokens (sum of q_seqlens)
#define NB 16          // batch
#define HQn 16         // query heads
#define HKn 8          // kv heads
#define Gn 2           // GQA group
#define Dn 256         // head dim
#define HID 3072
#define QKV_COLS 8192  // 4096 + 2048 + 2048
#define NCHUNK 16
#define CHUNKT 128

// counted vmcnt wait + scheduling fence (keeps ds_reads from hoisting above it)
#define WAIT_VM(n) do { \
    asm volatile("s_waitcnt vmcnt(" #n ")" ::: "memory"); \
    __builtin_amdgcn_sched_barrier(0); \
  } while (0)

// async global->LDS: each lane fetches 16B from its own gptr; HW writes
// LDS at (wave-uniform base) + lane*16.
__device__ __forceinline__ void gload16(const float* g, float* l) {
  __builtin_amdgcn_global_load_lds(
      (const __attribute__((address_space(1))) void*)g,
      (__attribute__((address_space(3))) void*)l, 16, 0, 0);
}

// ---------------- K1: QKV partial GEMM ----------------
// grid 512 = 32 col-tiles(256) * 16 k-splits(192), block 256
__global__ __launch_bounds__(256) void k1_qkv_gemm(
    const float* __restrict__ hs, const float* __restrict__ Wq,
    const float* __restrict__ Wk, const float* __restrict__ Wv,
    float* __restrict__ part1) {
  const int tile = blockIdx.x & 31;
  const int ks = blockIdx.x >> 5;
  const int c0 = tile << 8;
  const float* W; int ld, cw0;
  if (tile < 16)      { W = Wq; ld = 4096; cw0 = c0; }
  else if (tile < 24) { W = Wk; ld = 2048; cw0 = c0 - 4096; }
  else                { W = Wv; ld = 2048; cw0 = c0 - 6144; }
  const int kbase = ks * 192;
  const int cq = (threadIdx.x & 63) << 2;
  const int r0 = (threadIdx.x >> 6) * 10;
  __shared__ float h_lds[40][64];   // [token][k] : coalesced staging
  float acc[10][4];
#pragma unroll
  for (int r = 0; r < 10; ++r) { acc[r][0]=0.f; acc[r][1]=0.f; acc[r][2]=0.f; acc[r][3]=0.f; }
  for (int kc = 0; kc < 192; kc += 64) {
    __syncthreads();
    for (int i = threadIdx.x; i < 2560; i += 256) {
      int t = i >> 6, kk = i & 63;
      h_lds[t][kk] = hs[t * HID + kbase + kc + kk];
    }
    __syncthreads();
    const float* wp = W + (size_t)(kbase + kc) * ld + cw0 + cq;
#pragma unroll 8
    for (int kk = 0; kk < 64; ++kk) {
      float4 w4 = *reinterpret_cast<const float4*>(wp + (size_t)kk * ld);
#pragma unroll
      for (int r = 0; r < 10; ++r) {
        float h = h_lds[r0 + r][kk];
        acc[r][0] = fmaf(h, w4.x, acc[r][0]);
        acc[r][1] = fmaf(h, w4.y, acc[r][1]);
        acc[r][2] = fmaf(h, w4.z, acc[r][2]);
        acc[r][3] = fmaf(h, w4.w, acc[r][3]);
      }
    }
  }
#pragma unroll
  for (int r = 0; r < 10; ++r) {
    int t = r0 + r;
    float4 v = make_float4(acc[r][0], acc[r][1], acc[r][2], acc[r][3]);
    *reinterpret_cast<float4*>(&part1[(size_t)(ks * TT + t) * QKV_COLS + c0 + cq]) = v;
  }
}

// ---------------- K2: k-split reduce + RoPE ----------------
// grid 1280 = 40 tokens * 32 tiles, block 256
__global__ __launch_bounds__(256) void k2_reduce_rope(
    const float* __restrict__ part1, const float* __restrict__ inv_freq,
    const int* __restrict__ pos_ids,
    float* __restrict__ qbuf, float* __restrict__ kbuf, float* __restrict__ vbuf) {
  const int t = blockIdx.x >> 5;
  const int tile = blockIdx.x & 31;
  const int c = (tile << 8) + threadIdx.x;
  float s = 0.f;
#pragma unroll
  for (int ks = 0; ks < 16; ++ks) s += part1[(size_t)(ks * TT + t) * QKV_COLS + c];
  __shared__ float sl[256];
  sl[threadIdx.x] = s;
  __syncthreads();
  if (tile < 24) {   // q or k head: apply neox RoPE
    const int d = threadIdx.x;
    const int d2 = d & 127;
    float fr = (float)pos_ids[t] * inv_freq[d2];
    float cs = cosf(fr), sn = sinf(fr);
    float v = (d < 128) ? (sl[d] * cs - sl[d + 128] * sn)
                        : (sl[d] * cs + sl[d - 128] * sn);
    if (tile < 16) qbuf[t * 4096 + (tile << 8) + d] = v * 0.0625f;  // fold 1/sqrt(D)
    else           kbuf[t * 2048 + ((tile - 16) << 8) + d] = v;
  } else {
    vbuf[t * 2048 + ((tile - 24) << 8) + threadIdx.x] = s;
  }
}

// ---------------- K3: flash-decode attention partials ----------------
// global_load_lds staging (VGPR-free MLP), counted vmcnt pipeline,
// pre-swizzled global source for bank-conflict-free LDS reads.
// grid 2048 = b(16)*hk(8)*chunk(16 of 128 toks), block 256 (4 waves)
__global__ __launch_bounds__(256) void k3_attn_partial(
    const float* __restrict__ qbuf, const float* __restrict__ kbuf,
    const float* __restrict__ vbuf, const float* __restrict__ k_cache,
    const float* __restrict__ v_cache, const int* __restrict__ blk_off,
    const int* __restrict__ q_start, const int* __restrict__ q_lens,
    const int* __restrict__ kv_lens,
    float* __restrict__ part_o, float* __restrict__ part_ml) {
  const int chunk = blockIdx.x & 15;
  const int hk = (blockIdx.x >> 4) & 7;
  const int b = blockIdx.x >> 7;
  const int kv_len = kv_lens[b];
  const int cs0 = chunk * CHUNKT;
  if (cs0 >= kv_len) return;
  const int q_cnt = q_lens[b];
  const int hist = kv_len - q_cnt;
  const int q0 = q_start[b];
  const int nq = q_cnt * 2;

  __shared__ float kv_lds[4][2][8][256];  // [wave][buf][row][swizzled floats] 64KB
  __shared__ float S_lds[128][8];         // scores -> p values (in place)
  __shared__ float red[32][8];
  __shared__ float Mg[8];

  const int tid = threadIdx.x;
  const int w = tid >> 6;
  const int lane = tid & 63;
  const int aa = lane >> 3;   // dgrp in score phase
  const int bb = lane & 7;    // qv in score phase
  // swizzle: 16B-unit u stored at LDS slot u^(u>>3&7). Staging lane l
  // (writes slot l) must fetch global unit 8*aa + (bb^aa).
  const int sw_foff = (((aa << 3) | (bb ^ aa)) << 2);

  // chunk spans exactly 2 cache blocks: preload both -> pure-arith addressing
  const int bi = (b << 5) + (cs0 >> 6);
  const int blk0v = blk_off[bi];
  const int blk1v = blk_off[bi + 1];
  const float* kb0  = k_cache + ((size_t)blk0v << 17) + ((size_t)hk << 8);
  const float* kb1  = k_cache + ((size_t)blk1v << 17) + ((size_t)hk << 8);
  const float* vb0  = v_cache + ((size_t)blk0v << 17) + ((size_t)hk << 8);
  const float* vb1  = v_cache + ((size_t)blk1v << 17) + ((size_t)hk << 8);
  const float* knew = kbuf + ((size_t)q0 << 11) + ((size_t)hk << 8);
  const float* vnew = vbuf + ((size_t)q0 << 11) + ((size_t)hk << 8);

  auto rowK = [&](int s) -> const float* {
    if (s < hist) {
      const float* base = (s & 64) ? kb1 : kb0;
      return base + ((size_t)(s & 63) << 11);
    }
    return knew + ((size_t)(s - hist) << 11);
  };
  auto rowV = [&](int s) -> const float* {
    if (s < hist) {
      const float* base = (s & 64) ? vb1 : vb0;
      return base + ((size_t)(s & 63) << 11);
    }
    return vnew + ((size_t)(s - hist) << 11);
  };

  // init scores to -inf (rows never written must stay masked)
#pragma unroll
  for (int i = tid; i < 1024; i += 256) ((float*)S_lds)[i] = -1e30f;

  // Q fragments: lane (bb=qv, aa=dgrp) holds q[qv][aa*32 .. aa*32+31]
  const int qtok = min(bb >> 1, q_cnt - 1);
  const int g = bb & 1;
  float4 qf[8];
  {
    const float* qp = qbuf + (size_t)(q0 + qtok) * 4096 + (hk * Gn + g) * 256 + aa * 32;
#pragma unroll
    for (int j = 0; j < 8; ++j)
      qf[j] = *reinterpret_cast<const float4*>(qp + j * 4);
  }
  __syncthreads();   // S_lds init visible before any score writes

  const int sBeg = cs0 + w * 32;
  const int nv0 = kv_len - sBeg;
  const int nv = nv0 < 0 ? 0 : (nv0 > 32 ? 32 : nv0);

  auto stageK = [&](int bt, int t) {
    const int s = sBeg + (bt << 3) + t;
    gload16(rowK(s) + sw_foff, &kv_lds[w][bt & 1][t][0]);
  };
  auto scoreRow = [&](int bt, int t) {
    const int s = sBeg + (bt << 3) + t;
    const float* kr = &kv_lds[w][bt & 1][t][0];
    float s0 = 0.f, s1 = 0.f;
#pragma unroll
    for (int j = 0; j < 4; ++j) {
      float4 kf = *reinterpret_cast<const float4*>(kr + (aa << 5) + ((j ^ aa) << 2));
      s0 = fmaf(qf[j].x, kf.x, s0); s0 = fmaf(qf[j].y, kf.y, s0);
      s0 = fmaf(qf[j].z, kf.z, s0); s0 = fmaf(qf[j].w, kf.w, s0);
    }
#pragma unroll
    for (int j = 4; j < 8; ++j) {
      float4 kf = *reinterpret_cast<const float4*>(kr + (aa << 5) + ((j ^ aa) << 2));
      s1 = fmaf(qf[j].x, kf.x, s1); s1 = fmaf(qf[j].y, kf.y, s1);
      s1 = fmaf(qf[j].z, kf.z, s1); s1 = fmaf(qf[j].w, kf.w, s1);
    }
    float sc = s0 + s1;
    sc += __shfl_xor(sc, 8);
    sc += __shfl_xor(sc, 16);
    sc += __shfl_xor(sc, 32);
    if (lane < 8) {
      bool valid = (lane < nq) && ((s - hist) <= (lane >> 1));
      S_lds[(w << 5) + (bt << 3) + t][lane] = valid ? sc : -1e30f;
    }
  };

  // ---- K phase: stage->score pipeline, wave-private, no barriers ----
  if (nv == 32) {
#pragma unroll
    for (int t = 0; t < 8; ++t) stageK(0, t);
#pragma unroll
    for (int t = 0; t < 8; ++t) stageK(1, t);
    WAIT_VM(8);
#pragma unroll
    for (int t = 0; t < 8; ++t) scoreRow(0, t);
#pragma unroll
    for (int t = 0; t < 8; ++t) stageK(2, t);
    WAIT_VM(8);
#pragma unroll
    for (int t = 0; t < 8; ++t) scoreRow(1, t);
#pragma unroll
    for (int t = 0; t < 8; ++t) stageK(3, t);
    WAIT_VM(8);
#pragma unroll
    for (int t = 0; t < 8; ++t) scoreRow(2, t);
    WAIT_VM(0);
#pragma unroll
    for (int t = 0; t < 8; ++t) scoreRow(3, t);
  } else if (nv > 0) {
    for (int bt = 0; bt < 4; ++bt) {
      const int r0v = bt << 3;
      if (r0v >= nv) break;
      int cnt = nv - r0v; if (cnt > 8) cnt = 8;
      for (int t = 0; t < cnt; ++t) stageK(bt, t);
      WAIT_VM(0);
      for (int t = 0; t < cnt; ++t) scoreRow(bt, t);
    }
  }
  __syncthreads();

  // ---- softmax over the whole chunk. thread tid: qv2 = tid&7, grp = tid>>3 ----
  const int qv2 = tid & 7;
  const int grp = tid >> 3;
  {
    float mloc = -1e30f;
#pragma unroll
    for (int t = 0; t < 4; ++t) mloc = fmaxf(mloc, S_lds[grp * 4 + t][qv2]);
    red[grp][qv2] = mloc;
  }
  __syncthreads();
  if (tid < 8) {
    float M = -1e30f;
#pragma unroll
    for (int i = 0; i < 32; ++i) M = fmaxf(M, red[i][tid]);
    Mg[tid] = M;
  }
  __syncthreads();
  {
    float M = Mg[qv2];
    float lloc = 0.f;
#pragma unroll
    for (int t = 0; t < 4; ++t) {
      int s = grp * 4 + t;
      float p = __expf(S_lds[s][qv2] - M);
      S_lds[s][qv2] = p;
      lloc += p;
    }
    red[grp][qv2] = lloc;
  }
  __syncthreads();
  if (tid < 8) {
    float L = 0.f;
#pragma unroll
    for (int i = 0; i < 32; ++i) L += red[i][tid];
    int pidx = (((b * HKn + hk) * NCHUNK + chunk) << 3) + tid;
    part_ml[pidx * 2] = Mg[tid];
    part_ml[pidx * 2 + 1] = L;
  }

  // ---- V phase: stage->PV pipeline, wave-private ----
  float4 acc[8];
#pragma unroll
  for (int q = 0; q < 8; ++q) acc[q] = make_float4(0.f, 0.f, 0.f, 0.f);
  auto stageV = [&](int bt, int t) {
    const int s = sBeg + (bt << 3) + t;
    gload16(rowV(s) + sw_foff, &kv_lds[w][bt & 1][t][0]);
  };
  auto pvRow = [&](int bt, int t) {
    const int sl = (w << 5) + (bt << 3) + t;
    // lane's dims d4 = lane*4 live at swizzled slot sw_foff
    float4 vf = *reinterpret_cast<const float4*>(&kv_lds[w][bt & 1][t][sw_foff]);
    float4 p0 = *reinterpret_cast<const float4*>(&S_lds[sl][0]);
    float4 p1 = *reinterpret_cast<const float4*>(&S_lds[sl][4]);
    float pr[8] = {p0.x, p0.y, p0.z, p0.w, p1.x, p1.y, p1.z, p1.w};
#pragma unroll
    for (int q = 0; q < 8; ++q) {
      acc[q].x = fmaf(pr[q], vf.x, acc[q].x);
      acc[q].y = fmaf(pr[q], vf.y, acc[q].y);
      acc[q].z = fmaf(pr[q], vf.z, acc[q].z);
      acc[q].w = fmaf(pr[q], vf.w, acc[q].w);
    }
  };
  if (nv == 32) {
#pragma unroll
    for (int t = 0; t < 8; ++t) stageV(0, t);
#pragma unroll
    for (int t = 0; t < 8; ++t) stageV(1, t);
    WAIT_VM(8);
#pragma unroll
    for (int t = 0; t < 8; ++t) pvRow(0, t);
#pragma unroll
    for (int t = 0; t < 8; ++t) stageV(2, t);
    WAIT_VM(8);
#pragma unroll
    for (int t = 0; t < 8; ++t) pvRow(1, t);
#pragma unroll
    for (int t = 0; t < 8; ++t) stageV(3, t);
    WAIT_VM(8);
#pragma unroll
    for (int t = 0; t < 8; ++t) pvRow(2, t);
    WAIT_VM(0);
#pragma unroll
    for (int t = 0; t < 8; ++t) pvRow(3, t);
  } else if (nv > 0) {
    for (int bt = 0; bt < 4; ++bt) {
      const int r0v = bt << 3;
      if (r0v >= nv) break;
      int cnt = nv - r0v; if (cnt > 8) cnt = 8;
      for (int t = 0; t < cnt; ++t) stageV(bt, t);
      WAIT_VM(0);
      for (int t = 0; t < cnt; ++t) pvRow(bt, t);
    }
  }

  // ---- combine 4 wave-partials (same max within chunk -> plain sum) ----
  __syncthreads();   // all PV LDS reads done before o reuses kv_lds
  float* o_l = &kv_lds[0][0][0][0];   // [4][8][256] = 32KB
  const int d4 = lane << 2;
#pragma unroll
  for (int q = 0; q < 8; ++q)
    *reinterpret_cast<float4*>(&o_l[(w * 8 + q) * 256 + d4]) = acc[q];
  __syncthreads();
  for (int q = 0; q < nq; ++q) {
    float o = o_l[q * 256 + tid] + o_l[(8 + q) * 256 + tid]
            + o_l[(16 + q) * 256 + tid] + o_l[(24 + q) * 256 + tid];
    int pidx = (((b * HKn + hk) * NCHUNK + chunk) << 3) + q;
    part_o[(size_t)pidx * 256 + tid] = o;
  }
}

// ---------------- K4: combine chunk partials ----------------
// grid 1024 = b(16)*qtok(4)*h(16), block 64
__global__ __launch_bounds__(64) void k4_attn_reduce(
    const float* __restrict__ part_o, const float* __restrict__ part_ml,
    const int* __restrict__ q_start, const int* __restrict__ q_lens,
    const int* __restrict__ kv_lens, float* __restrict__ attn_out) {
  const int h = blockIdx.x & 15;
  const int qtok = (blockIdx.x >> 4) & 3;
  const int b = blockIdx.x >> 6;
  const int q_cnt = q_lens[b];
  if (qtok >= q_cnt) return;
  const int kv_len = kv_lens[b];
  const int nparts = (kv_len + CHUNKT - 1) >> 7;
  const int qv = qtok * 2 + (h & 1);
  const int hk = h >> 1;
  const int lane = threadIdx.x;
  const int pbase = ((b * HKn + hk) * NCHUNK) << 3;
  float2 mls[16];
#pragma unroll
  for (int i = 0; i < 16; ++i)
    if (i < nparts)
      mls[i] = *reinterpret_cast<const float2*>(&part_ml[(size_t)(pbase + (i << 3) + qv) * 2]);
  float M = -1e30f;
#pragma unroll
  for (int i = 0; i < 16; ++i)
    if (i < nparts) M = fmaxf(M, mls[i].x);
  float4 o = make_float4(0.f, 0.f, 0.f, 0.f);
  float L = 0.f;
#pragma unroll
  for (int i = 0; i < 16; ++i)
    if (i < nparts) {
      float corr = __expf(mls[i].x - M);
      L += corr * mls[i].y;
      float4 pv = *reinterpret_cast<const float4*>(
          &part_o[(size_t)(pbase + (i << 3) + qv) * 256 + (lane << 2)]);
      o.x = fmaf(corr, pv.x, o.x);
      o.y = fmaf(corr, pv.y, o.y);
      o.z = fmaf(corr, pv.z, o.z);
      o.w = fmaf(corr, pv.w, o.w);
    }
  float inv = 1.0f / L;
  int tr = q_start[b] + qtok;
  float4 res = make_float4(o.x * inv, o.y * inv, o.z * inv, o.w * inv);
  *reinterpret_cast<float4*>(&attn_out[((size_t)tr * HQn + h) * 256 + (lane << 2)]) = res;
}

// ---------------- K5: output GEMM partial (attn @ Wo) ----------------
// grid 384 = 12 col-tiles(256) * 32 k-splits(128), block 256
__global__ __launch_bounds__(256) void k5_out_gemm(
    const float* __restrict__ ain, const float* __restrict__ Wo,
    float* __restrict__ part2) {
  const int tile = blockIdx.x % 12;
  const int ks = blockIdx.x / 12;
  const int c0 = tile << 8;
  const int kbase = ks << 7;
  const int cq = (threadIdx.x & 63) << 2;
  const int r0 = (threadIdx.x >> 6) * 10;
  __shared__ float h_lds[40][64];
  float acc[10][4];
#pragma unroll
  for (int r = 0; r < 10; ++r) { acc[r][0]=0.f; acc[r][1]=0.f; acc[r][2]=0.f; acc[r][3]=0.f; }
  for (int kc = 0; kc < 128; kc += 64) {
    __syncthreads();
    for (int i = threadIdx.x; i < 2560; i += 256) {
      int t = i >> 6, kk = i & 63;
      h_lds[t][kk] = ain[(size_t)t * 4096 + kbase + kc + kk];
    }
    __syncthreads();
    const float* wp = Wo + (size_t)(kbase + kc) * 3072 + c0 + cq;
#pragma unroll 8
    for (int kk = 0; kk < 64; ++kk) {
      float4 w4 = *reinterpret_cast<const float4*>(wp + (size_t)kk * 3072);
#pragma unroll
      for (int r = 0; r < 10; ++r) {
        float h = h_lds[r0 + r][kk];
        acc[r][0] = fmaf(h, w4.x, acc[r][0]);
        acc[r][1] = fmaf(h, w4.y, acc[r][1]);
        acc[r][2] = fmaf(h, w4.z, acc[r][2]);
        acc[r][3] = fmaf(h, w4.w, acc[r][3]);
      }
    }
  }
#pragma unroll
  for (int r = 0; r < 10; ++r) {
    int t = r0 + r;
    float4 v = make_float4(acc[r][0], acc[r][1], acc[r][2], acc[r][3]);
    *reinterpret_cast<float4*>(&part2[(size_t)(ks * TT + t) * 3072 + c0 + cq]) = v;
  }
}

// ---------------- K6: final k-split reduce -> d_out ----------------
// grid 480, block 256  (40*3072 = 122880 outputs)
__global__ __launch_bounds__(256) void k6_final_reduce(
    const float* __restrict__ part2, float* __restrict__ out) {
  const int idx = blockIdx.x * 256 + threadIdx.x;
  float s = 0.f;
#pragma unroll
  for (int ks = 0; ks < 32; ++ks) s += part2[(size_t)ks * 122880 + idx];
  out[idx] = s;
}

extern "C" void kernel_launch(void* const* d_in, const int* in_sizes, int n_in,
                              void* d_out, int out_size, void* d_ws, size_t ws_size,
                              hipStream_t stream) {
  const float* hs       = (const float*)d_in[0];
  const float* Wq       = (const float*)d_in[1];
  const float* Wk       = (const float*)d_in[2];
  const float* Wv       = (const float*)d_in[3];
  const float* Wo       = (const float*)d_in[4];
  const float* k_cache  = (const float*)d_in[5];
  const float* v_cache  = (const float*)d_in[6];
  const float* inv_freq = (const float*)d_in[7];
  const int*   pos_ids  = (const int*)d_in[8];
  const int*   q_start  = (const int*)d_in[9];
  const int*   q_lens   = (const int*)d_in[10];
  const int*   kv_lens  = (const int*)d_in[11];
  const int*   blk_off  = (const int*)d_in[12];

  float* ws = (float*)d_ws;
  float* qbuf     = ws;                 // 40*4096          = 163840
  float* kbuf     = ws + 163840;        // 40*2048          =  81920
  float* vbuf     = ws + 245760;        // 40*2048          =  81920
  float* attn_out = ws + 327680;        // 40*4096          = 163840
  float* big      = ws + 491520;        // reused region (5242880 floats)
  float* part1    = big;                // 16*40*8192
  float* part_o   = big;                // 16384*256
  float* part_ml  = big + 4194304;      // 16384*2
  float* part2    = big;                // 32*40*3072
  float* out      = (float*)d_out;

  k1_qkv_gemm<<<512, 256, 0, stream>>>(hs, Wq, Wk, Wv, part1);
  k2_reduce_rope<<<1280, 256, 0, stream>>>(part1, inv_freq, pos_ids, qbuf, kbuf, vbuf);
  k3_attn_partial<<<2048, 256, 0, stream>>>(qbuf, kbuf, vbuf, k_cache, v_cache,
                                            blk_off, q_start, q_lens, kv_lens,
                                            part_o, part_ml);
  k4_attn_reduce<<<1024, 64, 0, stream>>>(part_o, part_ml, q_start, q_lens,
                                          kv_lens, attn_out);
  k5_out_gemm<<<384, 256, 0, stream>>>(attn_out, Wo, part2);
  k6_final_reduce<<<480, 256, 0, stream>>>(part2, out);
}

// Round 6
// 290.565 us; speedup vs baseline: 1.5213x; 1.0250x over previous
//
#include <hip/hip_runtime.h>
#include <math.h>

#define TT 40          // total query tokens (sum of q_seqlens)
#define NB 16          // batch
#define HQn 16         // query heads
#define HKn 8          // kv heads
#define Gn 2           // GQA group
#define Dn 256         // head dim
#define HID 3072
#define QKV_COLS 8192  // 4096 + 2048 + 2048
#define NCHUNK 16
#define CHUNKT 128

// ---------------- K1: QKV partial GEMM ----------------
// grid 512 = 32 col-tiles(256) * 16 k-splits(192), block 256
__global__ __launch_bounds__(256) void k1_qkv_gemm(
    const float* __restrict__ hs, const float* __restrict__ Wq,
    const float* __restrict__ Wk, const float* __restrict__ Wv,
    float* __restrict__ part1) {
  const int tile = blockIdx.x & 31;
  const int ks = blockIdx.x >> 5;
  const int c0 = tile << 8;
  const float* W; int ld, cw0;
  if (tile < 16)      { W = Wq; ld = 4096; cw0 = c0; }
  else if (tile < 24) { W = Wk; ld = 2048; cw0 = c0 - 4096; }
  else                { W = Wv; ld = 2048; cw0 = c0 - 6144; }
  const int kbase = ks * 192;
  const int cq = (threadIdx.x & 63) << 2;
  const int r0 = (threadIdx.x >> 6) * 10;
  __shared__ float h_lds[40][64];   // [token][k] : coalesced staging
  float acc[10][4];
#pragma unroll
  for (int r = 0; r < 10; ++r) { acc[r][0]=0.f; acc[r][1]=0.f; acc[r][2]=0.f; acc[r][3]=0.f; }
  for (int kc = 0; kc < 192; kc += 64) {
    __syncthreads();
    for (int i = threadIdx.x; i < 2560; i += 256) {
      int t = i >> 6, kk = i & 63;
      h_lds[t][kk] = hs[t * HID + kbase + kc + kk];
    }
    __syncthreads();
    const float* wp = W + (size_t)(kbase + kc) * ld + cw0 + cq;
#pragma unroll 8
    for (int kk = 0; kk < 64; ++kk) {
      float4 w4 = *reinterpret_cast<const float4*>(wp + (size_t)kk * ld);
#pragma unroll
      for (int r = 0; r < 10; ++r) {
        float h = h_lds[r0 + r][kk];
        acc[r][0] = fmaf(h, w4.x, acc[r][0]);
        acc[r][1] = fmaf(h, w4.y, acc[r][1]);
        acc[r][2] = fmaf(h, w4.z, acc[r][2]);
        acc[r][3] = fmaf(h, w4.w, acc[r][3]);
      }
    }
  }
#pragma unroll
  for (int r = 0; r < 10; ++r) {
    int t = r0 + r;
    float4 v = make_float4(acc[r][0], acc[r][1], acc[r][2], acc[r][3]);
    *reinterpret_cast<float4*>(&part1[(size_t)(ks * TT + t) * QKV_COLS + c0 + cq]) = v;
  }
}

// ---------------- K2: k-split reduce + RoPE ----------------
// grid 1280 = 40 tokens * 32 tiles, block 256
__global__ __launch_bounds__(256) void k2_reduce_rope(
    const float* __restrict__ part1, const float* __restrict__ inv_freq,
    const int* __restrict__ pos_ids,
    float* __restrict__ qbuf, float* __restrict__ kbuf, float* __restrict__ vbuf) {
  const int t = blockIdx.x >> 5;
  const int tile = blockIdx.x & 31;
  const int c = (tile << 8) + threadIdx.x;
  float s = 0.f;
#pragma unroll
  for (int ks = 0; ks < 16; ++ks) s += part1[(size_t)(ks * TT + t) * QKV_COLS + c];
  __shared__ float sl[256];
  sl[threadIdx.x] = s;
  __syncthreads();
  if (tile < 24) {   // q or k head: apply neox RoPE
    const int d = threadIdx.x;
    const int d2 = d & 127;
    float fr = (float)pos_ids[t] * inv_freq[d2];
    float cs = cosf(fr), sn = sinf(fr);
    float v = (d < 128) ? (sl[d] * cs - sl[d + 128] * sn)
                        : (sl[d] * cs + sl[d - 128] * sn);
    if (tile < 16) qbuf[t * 4096 + (tile << 8) + d] = v * 0.0625f;  // fold 1/sqrt(D)
    else           kbuf[t * 2048 + ((tile - 16) << 8) + d] = v;
  } else {
    vbuf[t * 2048 + ((tile - 24) << 8) + threadIdx.x] = s;
  }
}

// ---------------- K3: flash-decode attention partials (v6) ----------------
// No K/V LDS staging: register outer-product score with direct coalesced
// global K loads; q broadcast from LDS; shuffle-light reduction; PV streams
// V straight from global. grid 2048 = b(16)*hk(8)*chunk(16), block 256.
__global__ __launch_bounds__(256) void k3_attn_partial(
    const float* __restrict__ qbuf, const float* __restrict__ kbuf,
    const float* __restrict__ vbuf, const float* __restrict__ k_cache,
    const float* __restrict__ v_cache, const int* __restrict__ blk_off,
    const int* __restrict__ q_start, const int* __restrict__ q_lens,
    const int* __restrict__ kv_lens,
    float* __restrict__ part_o, float* __restrict__ part_ml) {
  const int chunk = blockIdx.x & 15;
  const int hk = (blockIdx.x >> 4) & 7;
  const int b = blockIdx.x >> 7;
  const int kv_len = kv_lens[b];
  const int cs0 = chunk * CHUNKT;
  if (cs0 >= kv_len) return;
  const int q_cnt = q_lens[b];
  const int hist = kv_len - q_cnt;
  const int q0 = q_start[b];
  const int nq = q_cnt * 2;

  __shared__ float q_lds[8][256];     // 8 KB
  __shared__ float S2[2][128][8];     // 8 KB: two half-sums -> p values
  __shared__ float red[32][8];        // 1 KB
  __shared__ float Mg[8];
  __shared__ float obuf[4][8][256];   // 32 KB wave partial outputs

  const int tid = threadIdx.x;
  const int w = tid >> 6;
  const int lane = tid & 63;
  const int tp = lane & 7;    // token quad within wave's 32
  const int qd = lane >> 3;   // interleaved 4-float dim slice

  // chunk spans exactly 2 cache blocks: preload both -> pure-arith addressing
  const int bi = (b << 5) + (cs0 >> 6);
  const int blk0v = blk_off[bi];
  const int blk1v = blk_off[bi + 1];
  const float* kb0  = k_cache + ((size_t)blk0v << 17) + ((size_t)hk << 8);
  const float* kb1  = k_cache + ((size_t)blk1v << 17) + ((size_t)hk << 8);
  const float* vb0  = v_cache + ((size_t)blk0v << 17) + ((size_t)hk << 8);
  const float* vb1  = v_cache + ((size_t)blk1v << 17) + ((size_t)hk << 8);
  const float* knew = kbuf + ((size_t)q0 << 11) + ((size_t)hk << 8);
  const float* vnew = vbuf + ((size_t)q0 << 11) + ((size_t)hk << 8);

  auto rowK = [&](int s) -> const float* {
    if (s < hist) {
      const float* base = (s & 64) ? kb1 : kb0;
      return base + ((size_t)(s & 63) << 11);
    }
    return knew + ((size_t)(s - hist) << 11);
  };
  auto rowV = [&](int s) -> const float* {
    if (s < hist) {
      const float* base = (s & 64) ? vb1 : vb0;
      return base + ((size_t)(s & 63) << 11);
    }
    return vnew + ((size_t)(s - hist) << 11);
  };

  // stage Q (scale already folded): 8 qv rows x 256
  for (int i = tid; i < 2048; i += 256) {
    int qv = i >> 8, d = i & 255;
    int qtok = min(qv >> 1, q_cnt - 1);
    q_lds[qv][d] = qbuf[(size_t)(q0 + qtok) * 4096 + (hk * Gn + (qv & 1)) * 256 + d];
  }
  __syncthreads();

  const int sBeg = cs0 + (w << 5);

  // ---- score phase: lane owns 4 tokens x 32 dims (stride-32 interleave) ----
  const float* kr[4];
#pragma unroll
  for (int tt = 0; tt < 4; ++tt) {
    int s = sBeg + (tp << 2) + tt;
    int sc = s < kv_len ? s : kv_len - 1;   // clamp; masked in softmax
    kr[tt] = rowK(sc) + (qd << 2);
  }
  float acc[4][8];
#pragma unroll
  for (int tt = 0; tt < 4; ++tt)
#pragma unroll
    for (int qv = 0; qv < 8; ++qv) acc[tt][qv] = 0.f;

#pragma unroll
  for (int c = 0; c < 8; ++c) {
    float4 kf[4];
#pragma unroll
    for (int tt = 0; tt < 4; ++tt)
      kf[tt] = *reinterpret_cast<const float4*>(kr[tt] + (c << 5));
#pragma unroll
    for (int qv = 0; qv < 8; ++qv) {
      float4 qf = *reinterpret_cast<const float4*>(&q_lds[qv][(qd << 2) + (c << 5)]);
#pragma unroll
      for (int tt = 0; tt < 4; ++tt) {
        acc[tt][qv] = fmaf(qf.x, kf[tt].x, acc[tt][qv]);
        acc[tt][qv] = fmaf(qf.y, kf[tt].y, acc[tt][qv]);
        acc[tt][qv] = fmaf(qf.z, kf[tt].z, acc[tt][qv]);
        acc[tt][qv] = fmaf(qf.w, kf[tt].w, acc[tt][qv]);
      }
    }
  }
  // reduce over qd bits {3,4}; bit 5 resolved in softmax (two half-sums)
#pragma unroll
  for (int tt = 0; tt < 4; ++tt)
#pragma unroll
    for (int qv = 0; qv < 8; ++qv) {
      float v = acc[tt][qv];
      v += __shfl_xor(v, 8);
      v += __shfl_xor(v, 16);
      acc[tt][qv] = v;
    }
  if ((lane & 24) == 0) {
    const int h = lane >> 5;
#pragma unroll
    for (int tt = 0; tt < 4; ++tt) {
      int srel = (w << 5) + (tp << 2) + tt;
      *reinterpret_cast<float4*>(&S2[h][srel][0]) =
          make_float4(acc[tt][0], acc[tt][1], acc[tt][2], acc[tt][3]);
      *reinterpret_cast<float4*>(&S2[h][srel][4]) =
          make_float4(acc[tt][4], acc[tt][5], acc[tt][6], acc[tt][7]);
    }
  }
  __syncthreads();

  // ---- softmax over the whole chunk. thread: qv2 = tid&7, grp = tid>>3 ----
  const int qv2 = tid & 7;
  const int grp = tid >> 3;
  float sv[4];
  {
    float mloc = -1e30f;
#pragma unroll
    for (int t = 0; t < 4; ++t) {
      int sl = (grp << 2) + t;
      float v = S2[0][sl][qv2] + S2[1][sl][qv2];
      bool valid = (qv2 < nq) && ((cs0 + sl - hist) <= (qv2 >> 1));
      v = valid ? v : -1e30f;
      sv[t] = v;
      mloc = fmaxf(mloc, v);
    }
    red[grp][qv2] = mloc;
  }
  __syncthreads();
  if (tid < 8) {
    float M = -1e30f;
#pragma unroll
    for (int i = 0; i < 32; ++i) M = fmaxf(M, red[i][tid]);
    Mg[tid] = M;
  }
  __syncthreads();
  {
    float M = Mg[qv2];
    float lloc = 0.f;
#pragma unroll
    for (int t = 0; t < 4; ++t) {
      float p = __expf(sv[t] - M);
      S2[0][(grp << 2) + t][qv2] = p;
      lloc += p;
    }
    red[grp][qv2] = lloc;
  }
  __syncthreads();
  if (tid < 8) {
    float L = 0.f;
#pragma unroll
    for (int i = 0; i < 32; ++i) L += red[i][tid];
    int pidx = (((b * HKn + hk) * NCHUNK + chunk) << 3) + tid;
    part_ml[pidx * 2] = Mg[tid];
    part_ml[pidx * 2 + 1] = L;
  }

  // ---- PV phase: lane owns dims d4 = lane*4; V streamed from global ----
  float4 pacc[8];
#pragma unroll
  for (int q = 0; q < 8; ++q) pacc[q] = make_float4(0.f, 0.f, 0.f, 0.f);
  const int d4 = lane << 2;
#pragma unroll 4
  for (int t = 0; t < 32; ++t) {
    int s = sBeg + t;
    int sc = s < kv_len ? s : kv_len - 1;
    float4 vf = *reinterpret_cast<const float4*>(rowV(sc) + d4);
    int srel = (w << 5) + t;
    float4 p0 = *reinterpret_cast<const float4*>(&S2[0][srel][0]);
    float4 p1 = *reinterpret_cast<const float4*>(&S2[0][srel][4]);
    float pr[8] = {p0.x, p0.y, p0.z, p0.w, p1.x, p1.y, p1.z, p1.w};
#pragma unroll
    for (int q = 0; q < 8; ++q) {
      pacc[q].x = fmaf(pr[q], vf.x, pacc[q].x);
      pacc[q].y = fmaf(pr[q], vf.y, pacc[q].y);
      pacc[q].z = fmaf(pr[q], vf.z, pacc[q].z);
      pacc[q].w = fmaf(pr[q], vf.w, pacc[q].w);
    }
  }
#pragma unroll
  for (int q = 0; q < 8; ++q)
    *reinterpret_cast<float4*>(&obuf[w][q][d4]) = pacc[q];
  __syncthreads();

  // combine 4 wave-partials (same max within chunk -> plain sum)
  for (int q = 0; q < nq; ++q) {
    float o = obuf[0][q][tid] + obuf[1][q][tid] + obuf[2][q][tid] + obuf[3][q][tid];
    int pidx = (((b * HKn + hk) * NCHUNK + chunk) << 3) + q;
    part_o[(size_t)pidx * 256 + tid] = o;
  }
}

// ---------------- K4: combine chunk partials ----------------
// grid 1024 = b(16)*qtok(4)*h(16), block 64
__global__ __launch_bounds__(64) void k4_attn_reduce(
    const float* __restrict__ part_o, const float* __restrict__ part_ml,
    const int* __restrict__ q_start, const int* __restrict__ q_lens,
    const int* __restrict__ kv_lens, float* __restrict__ attn_out) {
  const int h = blockIdx.x & 15;
  const int qtok = (blockIdx.x >> 4) & 3;
  const int b = blockIdx.x >> 6;
  const int q_cnt = q_lens[b];
  if (qtok >= q_cnt) return;
  const int kv_len = kv_lens[b];
  const int nparts = (kv_len + CHUNKT - 1) >> 7;
  const int qv = qtok * 2 + (h & 1);
  const int hk = h >> 1;
  const int lane = threadIdx.x;
  const int pbase = ((b * HKn + hk) * NCHUNK) << 3;
  float2 mls[16];
#pragma unroll
  for (int i = 0; i < 16; ++i)
    if (i < nparts)
      mls[i] = *reinterpret_cast<const float2*>(&part_ml[(size_t)(pbase + (i << 3) + qv) * 2]);
  float M = -1e30f;
#pragma unroll
  for (int i = 0; i < 16; ++i)
    if (i < nparts) M = fmaxf(M, mls[i].x);
  float4 o = make_float4(0.f, 0.f, 0.f, 0.f);
  float L = 0.f;
#pragma unroll
  for (int i = 0; i < 16; ++i)
    if (i < nparts) {
      float corr = __expf(mls[i].x - M);
      L += corr * mls[i].y;
      float4 pv = *reinterpret_cast<const float4*>(
          &part_o[(size_t)(pbase + (i << 3) + qv) * 256 + (lane << 2)]);
      o.x = fmaf(corr, pv.x, o.x);
      o.y = fmaf(corr, pv.y, o.y);
      o.z = fmaf(corr, pv.z, o.z);
      o.w = fmaf(corr, pv.w, o.w);
    }
  float inv = 1.0f / L;
  int tr = q_start[b] + qtok;
  float4 res = make_float4(o.x * inv, o.y * inv, o.z * inv, o.w * inv);
  *reinterpret_cast<float4*>(&attn_out[((size_t)tr * HQn + h) * 256 + (lane << 2)]) = res;
}

// ---------------- K5: output GEMM partial (attn @ Wo) ----------------
// grid 384 = 12 col-tiles(256) * 32 k-splits(128), block 256
__global__ __launch_bounds__(256) void k5_out_gemm(
    const float* __restrict__ ain, const float* __restrict__ Wo,
    float* __restrict__ part2) {
  const int tile = blockIdx.x % 12;
  const int ks = blockIdx.x / 12;
  const int c0 = tile << 8;
  const int kbase = ks << 7;
  const int cq = (threadIdx.x & 63) << 2;
  const int r0 = (threadIdx.x >> 6) * 10;
  __shared__ float h_lds[40][64];
  float acc[10][4];
#pragma unroll
  for (int r = 0; r < 10; ++r) { acc[r][0]=0.f; acc[r][1]=0.f; acc[r][2]=0.f; acc[r][3]=0.f; }
  for (int kc = 0; kc < 128; kc += 64) {
    __syncthreads();
    for (int i = threadIdx.x; i < 2560; i += 256) {
      int t = i >> 6, kk = i & 63;
      h_lds[t][kk] = ain[(size_t)t * 4096 + kbase + kc + kk];
    }
    __syncthreads();
    const float* wp = Wo + (size_t)(kbase + kc) * 3072 + c0 + cq;
#pragma unroll 8
    for (int kk = 0; kk < 64; ++kk) {
      float4 w4 = *reinterpret_cast<const float4*>(wp + (size_t)kk * 3072);
#pragma unroll
      for (int r = 0; r < 10; ++r) {
        float h = h_lds[r0 + r][kk];
        acc[r][0] = fmaf(h, w4.x, acc[r][0]);
        acc[r][1] = fmaf(h, w4.y, acc[r][1]);
        acc[r][2] = fmaf(h, w4.z, acc[r][2]);
        acc[r][3] = fmaf(h, w4.w, acc[r][3]);
      }
    }
  }
#pragma unroll
  for (int r = 0; r < 10; ++r) {
    int t = r0 + r;
    float4 v = make_float4(acc[r][0], acc[r][1], acc[r][2], acc[r][3]);
    *reinterpret_cast<float4*>(&part2[(size_t)(ks * TT + t) * 3072 + c0 + cq]) = v;
  }
}

// ---------------- K6: final k-split reduce -> d_out ----------------
// grid 480, block 256  (40*3072 = 122880 outputs)
__global__ __launch_bounds__(256) void k6_final_reduce(
    const float* __restrict__ part2, float* __restrict__ out) {
  const int idx = blockIdx.x * 256 + threadIdx.x;
  float s = 0.f;
#pragma unroll
  for (int ks = 0; ks < 32; ++ks) s += part2[(size_t)ks * 122880 + idx];
  out[idx] = s;
}

extern "C" void kernel_launch(void* const* d_in, const int* in_sizes, int n_in,
                              void* d_out, int out_size, void* d_ws, size_t ws_size,
                              hipStream_t stream) {
  const float* hs       = (const float*)d_in[0];
  const float* Wq       = (const float*)d_in[1];
  const float* Wk       = (const float*)d_in[2];
  const float* Wv       = (const float*)d_in[3];
  const float* Wo       = (const float*)d_in[4];
  const float* k_cache  = (const float*)d_in[5];
  const float* v_cache  = (const float*)d_in[6];
  const float* inv_freq = (const float*)d_in[7];
  const int*   pos_ids  = (const int*)d_in[8];
  const int*   q_start  = (const int*)d_in[9];
  const int*   q_lens   = (const int*)d_in[10];
  const int*   kv_lens  = (const int*)d_in[11];
  const int*   blk_off  = (const int*)d_in[12];

  float* ws = (float*)d_ws;
  float* qbuf     = ws;                 // 40*4096          = 163840
  float* kbuf     = ws + 163840;        // 40*2048          =  81920
  float* vbuf     = ws + 245760;        // 40*2048          =  81920
  float* attn_out = ws + 327680;        // 40*4096          = 163840
  float* big      = ws + 491520;        // reused region (5242880 floats)
  float* part1    = big;                // 16*40*8192
  float* part_o   = big;                // 16384*256
  float* part_ml  = big + 4194304;      // 16384*2
  float* part2    = big;                // 32*40*3072
  float* out      = (float*)d_out;

  k1_qkv_gemm<<<512, 256, 0, stream>>>(hs, Wq, Wk, Wv, part1);
  k2_reduce_rope<<<1280, 256, 0, stream>>>(part1, inv_freq, pos_ids, qbuf, kbuf, vbuf);
  k3_attn_partial<<<2048, 256, 0, stream>>>(qbuf, kbuf, vbuf, k_cache, v_cache,
                                            blk_off, q_start, q_lens, kv_lens,
                                            part_o, part_ml);
  k4_attn_reduce<<<1024, 64, 0, stream>>>(part_o, part_ml, q_start, q_lens,
                                          kv_lens, attn_out);
  k5_out_gemm<<<384, 256, 0, stream>>>(attn_out, Wo, part2);
  k6_final_reduce<<<480, 256, 0, stream>>>(part2, out);
}